// Round 3
// baseline (89142.877 us; speedup 1.0000x reference)
//
#include <hip/hip_runtime.h>
#include <stdint.h>

// LSTM_29042568856007: B=64, T=4096, D=256, H=256.
// Round 3: back to 1 WG/batch (64 WGs, no cross-WG sync — round 2 showed
// per-step exchange costs ~6us/step through IC). Attack the per-CU weight
// stream (L2 ~60 B/cyc/CU) instead:
//   (a) x-gate batching: compute x-part of gates for NX=8 steps per W_ih
//       pass -> W_ih stream amortized 512 -> 64 KB/step.
//   (b) W_hh k<144 held in VGPRs (18 uint4/thread, loaded once) ->
//       streamed W_hh drops 512 -> 224 KB/step.
// Step becomes VALU-bound (~7K cyc): unpack+fma inner loop.

#define LSTM_B 64
#define LSTM_T 4096
#define LSTM_D 256
#define LSTM_H 256
#define NX 8           // timesteps per W_ih pass
#define NV 18          // uint4s of W_hh per thread held in VGPRs (144 weights)
#define NS (32 - NV)   // streamed uint4s per thread per step (112 weights)

// ws: uint4 Wp[64][1024]  (k4, r), 1 MiB packed bf16 pairs.
//   k4 in [0,32): W_ih, k = 8*k4 + ...; k4 in [32,64): W_hh.

static __device__ __forceinline__ uint32_t f32_to_bf16_rne(float f) {
    uint32_t u = __float_as_uint(f);
    uint32_t rounding = 0x7fffu + ((u >> 16) & 1u);
    return (u + rounding) >> 16;
}

__global__ __launch_bounds__(256) void prep_weights(
    const float* __restrict__ W_ih, const float* __restrict__ W_hh,
    uint32_t* __restrict__ Wp)
{
    int idx = blockIdx.x * blockDim.x + threadIdx.x;  // u32 index in [0, 262144)
    if (idx >= 64 * 1024 * 4) return;
    int j  = idx & 3;            // which u32 inside the uint4
    int r  = (idx >> 2) & 1023;  // gate row
    int k4 = idx >> 12;          // 8-wide k group
    int k  = ((k4 & 31) << 3) + (j << 1);
    const float* W = (k4 < 32) ? W_ih : W_hh;
    float f0 = W[r * 256 + k];
    float f1 = W[r * 256 + k + 1];
    Wp[idx] = f32_to_bf16_rne(f0) | (f32_to_bf16_rne(f1) << 16);
}

static __device__ __forceinline__ float sigmoidf_(float x) {
    return 1.0f / (1.0f + __expf(-x));
}
static __device__ __forceinline__ float tanhf_(float x) {
    float ax = fabsf(x);
    float e  = __expf(-2.0f * ax);
    float t  = (1.0f - e) / (1.0f + e);
    return copysignf(t, x);
}

// 8 bf16 weights (uint4 w) * 8 fp32 activations, two accumulators for ILP
#define UNPACK_FMA8(w, a0, a1)                                         \
    acc0 = fmaf(__uint_as_float((w).x << 16),          (a0).x, acc0);  \
    acc1 = fmaf(__uint_as_float((w).x & 0xffff0000u),  (a0).y, acc1);  \
    acc0 = fmaf(__uint_as_float((w).y << 16),          (a0).z, acc0);  \
    acc1 = fmaf(__uint_as_float((w).y & 0xffff0000u),  (a0).w, acc1);  \
    acc0 = fmaf(__uint_as_float((w).z << 16),          (a1).x, acc0);  \
    acc1 = fmaf(__uint_as_float((w).z & 0xffff0000u),  (a1).y, acc1);  \
    acc0 = fmaf(__uint_as_float((w).w << 16),          (a1).z, acc0);  \
    acc1 = fmaf(__uint_as_float((w).w & 0xffff0000u),  (a1).w, acc1);

__global__ __launch_bounds__(1024) void lstm_r3(
    const float* __restrict__ xs,     // [B, T, D]
    const float* __restrict__ bias_g, // [4H]
    const uint4* __restrict__ Wp,     // [64][1024]
    float* __restrict__ out)          // h[B,H] then c[B,H]
{
    __shared__ __align__(16) float x_s[NX * LSTM_D];    // 8 KiB
    __shared__ __align__(16) float xg_s[NX * 1024];     // 32 KiB
    __shared__ __align__(16) float h_s[LSTM_H];         // 1 KiB
    __shared__ __align__(16) float g_s[1024];           // 4 KiB

    const int tid = threadIdx.x;   // gate row r = tid
    const int b   = blockIdx.x;    // batch element

    const float bias = bias_g[tid];
    const float* xrow = xs + (size_t)b * LSTM_T * LSTM_D;

    // --- one-time: W_hh k in [0,144) into VGPRs ---
    uint4 wreg[NV];
    #pragma unroll
    for (int i = 0; i < NV; ++i) wreg[i] = Wp[(32 + i) * 1024 + tid];

    const uint4* Wih = Wp + tid;                       // + k4*1024, k4<32
    const uint4* Whs = Wp + (32 + NV) * 1024 + tid;    // streamed tail, + i*1024

    if (tid < LSTM_H) h_s[tid] = 0.0f;
    float c = 0.0f, hlast = 0.0f;

    // prefetch group 0's x (NX*256 floats = NX*64 float4)
    float4 xpre;
    if (tid < NX * 64) xpre = ((const float4*)xrow)[tid];

    for (int tg = 0; tg < LSTM_T / NX; ++tg) {
        // ---- stage x for this group, prefetch next group ----
        if (tid < NX * 64) {
            ((float4*)x_s)[tid] = xpre;
            int ng = (tg + 1 < LSTM_T / NX) ? tg + 1 : tg;
            xpre = ((const float4*)(xrow + (size_t)ng * NX * LSTM_D))[tid];
        }
        __syncthreads();   // bar 1: x_s ready (and h_s init on first iter)

        // ---- x-pass: xg[tt][tid] = bias + W_ih[tid,:] . x_t  for NX steps ----
        float xacc[NX];
        #pragma unroll
        for (int tt = 0; tt < NX; ++tt) xacc[tt] = bias;
        #pragma unroll 2
        for (int k4 = 0; k4 < 32; ++k4) {
            uint4 w = Wih[k4 << 10];
            float w0 = __uint_as_float(w.x << 16);
            float w1 = __uint_as_float(w.x & 0xffff0000u);
            float w2 = __uint_as_float(w.y << 16);
            float w3 = __uint_as_float(w.y & 0xffff0000u);
            float w4 = __uint_as_float(w.z << 16);
            float w5 = __uint_as_float(w.z & 0xffff0000u);
            float w6 = __uint_as_float(w.w << 16);
            float w7 = __uint_as_float(w.w & 0xffff0000u);
            #pragma unroll
            for (int tt = 0; tt < NX; ++tt) {
                const float4* xt4 = (const float4*)(x_s + (tt << 8));
                float4 a0 = xt4[2 * k4];
                float4 a1 = xt4[2 * k4 + 1];
                float s = xacc[tt];
                s = fmaf(w0, a0.x, s); s = fmaf(w1, a0.y, s);
                s = fmaf(w2, a0.z, s); s = fmaf(w3, a0.w, s);
                s = fmaf(w4, a1.x, s); s = fmaf(w5, a1.y, s);
                s = fmaf(w6, a1.z, s); s = fmaf(w7, a1.w, s);
                xacc[tt] = s;
            }
        }
        #pragma unroll
        for (int tt = 0; tt < NX; ++tt) xg_s[(tt << 10) + tid] = xacc[tt];
        __syncthreads();   // bar 2: xg_s ready

        // ---- NX recurrence steps ----
        for (int tt = 0; tt < NX; ++tt) {
            float acc0 = xg_s[(tt << 10) + tid];
            float acc1 = 0.0f;
            const float4* h4 = (const float4*)h_s;

            // streamed tail: 2-deep load pipeline, issued before VGPR block
            uint4 wc = Whs[0];
            uint4 wn = Whs[1024];

            // VGPR-resident part: k in [0, 8*NV)
            #pragma unroll
            for (int i = 0; i < NV; ++i) {
                uint4 w = wreg[i];
                float4 a0 = h4[2 * i];
                float4 a1 = h4[2 * i + 1];
                UNPACK_FMA8(w, a0, a1)
            }
            // streamed part: k in [8*NV, 256)
            #pragma unroll
            for (int i = 0; i < NS; ++i) {
                uint4 w = wc;
                wc = wn;
                if (i + 2 < NS) wn = Whs[(i + 2) * 1024];
                float4 a0 = h4[2 * (NV + i)];
                float4 a1 = h4[2 * (NV + i) + 1];
                UNPACK_FMA8(w, a0, a1)
            }
            g_s[tid] = acc0 + acc1;
            __syncthreads();   // bar G: gates ready

            if (tid < LSTM_H) {
                float gi = g_s[tid];
                float gf = g_s[tid + 256];
                float gg = g_s[tid + 512];
                float go = g_s[tid + 768];
                c = sigmoidf_(gf) * c + sigmoidf_(gi) * tanhf_(gg);
                hlast = sigmoidf_(go) * tanhf_(c);
                h_s[tid] = hlast;
            }
            __syncthreads();   // bar H: h_t+1 visible for next dot
        }
    }

    if (tid < LSTM_H) {
        out[b * LSTM_H + tid]                    = hlast;  // h_T
        out[LSTM_B * LSTM_H + b * LSTM_H + tid]  = c;      // c_T
    }
}

extern "C" void kernel_launch(void* const* d_in, const int* in_sizes, int n_in,
                              void* d_out, int out_size, void* d_ws, size_t ws_size,
                              hipStream_t stream) {
    const float* xs   = (const float*)d_in[0];  // [64,4096,256]
    const float* W_ih = (const float*)d_in[1];  // [1024,256]
    const float* W_hh = (const float*)d_in[2];  // [1024,256]
    const float* b    = (const float*)d_in[3];  // [1024]
    float* out = (float*)d_out;
    uint32_t* Wp = (uint32_t*)d_ws;             // 1 MiB packed bf16 weights

    prep_weights<<<1024, 256, 0, stream>>>(W_ih, W_hh, Wp);
    lstm_r3<<<LSTM_B, 1024, 0, stream>>>(xs, b, (const uint4*)Wp, out);
}

// Round 4
// 22540.376 us; speedup vs baseline: 3.9548x; 3.9548x over previous
//
#include <hip/hip_runtime.h>
#include <hip/hip_fp16.h>
#include <stdint.h>

// LSTM_29042568856007: B=64, T=4096, D=256, H=256.
// Round 4: 1 WG/batch (64 WGs). f16 weights+activations with v_dot2_f32_f16
// (2 MAC/instr, fp32 acc, no unpack). NX=8 x-gate batching amortizes W_ih.
// NO register-resident weights (round 3: 1024-thr blocks cap at 64 VGPR ->
// wreg[18] spilled to scratch -> 80 GB HBM traffic).
// Per-CU stream: 512 KB W_hh + 64 KB W_ih = 576 KB/step @ ~55 B/cyc.

#define LSTM_B 64
#define LSTM_T 4096
#define LSTM_D 256
#define LSTM_H 256
#define NX 8
#define NG (LSTM_T / NX)

typedef __attribute__((ext_vector_type(2))) _Float16 half2_t;

static __device__ __forceinline__ float dot2(uint32_t w, uint32_t a, float acc) {
#if __has_builtin(__builtin_amdgcn_fdot2)
    return __builtin_amdgcn_fdot2(__builtin_bit_cast(half2_t, w),
                                  __builtin_bit_cast(half2_t, a), acc, false);
#else
    __half2 hw = __builtin_bit_cast(__half2, w);
    __half2 ha = __builtin_bit_cast(__half2, a);
    acc = fmaf(__low2float(hw), __low2float(ha), acc);
    acc = fmaf(__high2float(hw), __high2float(ha), acc);
    return acc;
#endif
}

// ws: uint4 Wp[64][1024]  (k4, r), 1 MiB packed f16 pairs.
//   k4 in [0,32): W_ih, k = 8*(k4&31)+...; k4 in [32,64): W_hh.
__global__ __launch_bounds__(256) void prep_weights(
    const float* __restrict__ W_ih, const float* __restrict__ W_hh,
    uint32_t* __restrict__ Wp)
{
    int idx = blockIdx.x * blockDim.x + threadIdx.x;  // uint index [0, 262144)
    if (idx >= 64 * 1024 * 4) return;
    int e  = idx & 3;
    int r  = (idx >> 2) & 1023;
    int k4 = idx >> 12;
    int k  = ((k4 & 31) << 3) + (e << 1);
    const float* W = (k4 < 32) ? W_ih : W_hh;
    uint32_t lo = (uint32_t)__half_as_ushort(__float2half(W[r * 256 + k]));
    uint32_t hi = (uint32_t)__half_as_ushort(__float2half(W[r * 256 + k + 1]));
    Wp[idx] = lo | (hi << 16);
}

static __device__ __forceinline__ float sigmoidf_(float x) {
    return 1.0f / (1.0f + __expf(-x));
}
static __device__ __forceinline__ float tanhf_(float x) {
    float ax = fabsf(x);
    float e  = __expf(-2.0f * ax);
    float t  = (1.0f - e) / (1.0f + e);
    return copysignf(t, x);
}

__global__ __launch_bounds__(1024) void lstm_r4(
    const float* __restrict__ xs,     // [B, T, D] fp32
    const float* __restrict__ bias_g, // [4H]
    const uint4* __restrict__ Wp,     // [64][1024] f16-pair octets
    float* __restrict__ out)          // h[B,H] then c[B,H]
{
    __shared__ __align__(16) uint32_t x_u[NX * 128];   // 4 KiB  (f16-packed x, 8 steps)
    __shared__ __align__(16) float    xg_s[NX * 1024]; // 32 KiB (x-part of gates, fp32)
    __shared__ __align__(16) uint32_t h_u[128];        // 512 B  (f16-packed h)
    __shared__ __align__(16) float    g_s[1024];       // 4 KiB  (gate partials)

    const int tid = threadIdx.x;   // gate row r = tid
    const int b   = blockIdx.x;    // batch element

    const float bias = bias_g[tid];
    const float* xrow = xs + (size_t)b * LSTM_T * LSTM_D;

    const uint4* Wih = Wp + tid;               // + (k4<<10), k4 in [0,32)
    const uint4* Whh = Wp + (32 << 10) + tid;  // + (k4<<10), k4 in [0,32)
    const uint4* x_u4 = (const uint4*)x_u;
    const uint4* h_u4 = (const uint4*)h_u;

    if (tid < 128) h_u[tid] = 0u;
    float c = 0.0f, hlast = 0.0f;

    // prefetch group 0's x: 8 steps * 256 floats = 1024 float2, one per thread
    float2 xpre = ((const float2*)xrow)[tid];

    for (int tg = 0; tg < NG; ++tg) {
        // ---- stage packed-f16 x for this group; prefetch next group ----
        {
            __half2 p = __floats2half2_rn(xpre.x, xpre.y);
            x_u[tid] = __builtin_bit_cast(uint32_t, p);  // tid = tt*128 + kpair
            int ng = (tg + 1 < NG) ? tg + 1 : tg;
            xpre = ((const float2*)(xrow + (size_t)ng * NX * LSTM_D))[tid];
        }
        __syncthreads();   // bar 1: x_u ready (and h_u init on first group)

        // ---- x-pass: xg[tt][tid] = bias + W_ih[tid,:].x_t for NX steps ----
        float xacc[NX];
        #pragma unroll
        for (int tt = 0; tt < NX; ++tt) xacc[tt] = bias;
        #pragma unroll 2
        for (int k4 = 0; k4 < 32; ++k4) {
            uint4 w = Wih[k4 << 10];
            #pragma unroll
            for (int tt = 0; tt < NX; ++tt) {
                uint4 xa = x_u4[tt * 32 + k4];   // wave-uniform -> broadcast
                float s = xacc[tt];
                s = dot2(w.x, xa.x, s);
                s = dot2(w.y, xa.y, s);
                s = dot2(w.z, xa.z, s);
                s = dot2(w.w, xa.w, s);
                xacc[tt] = s;
            }
        }
        #pragma unroll
        for (int tt = 0; tt < NX; ++tt) xg_s[(tt << 10) + tid] = xacc[tt];
        __syncthreads();   // bar 2: xg_s ready

        // ---- NX recurrence steps ----
        #pragma unroll 1
        for (int tt = 0; tt < NX; ++tt) {
            float acc0 = xg_s[(tt << 10) + tid];
            float acc1 = 0.0f;
            #pragma unroll 4
            for (int k4 = 0; k4 < 32; ++k4) {
                uint4 w  = Whh[k4 << 10];
                uint4 ha = h_u4[k4];             // wave-uniform -> broadcast
                acc0 = dot2(w.x, ha.x, acc0);
                acc1 = dot2(w.y, ha.y, acc1);
                acc0 = dot2(w.z, ha.z, acc0);
                acc1 = dot2(w.w, ha.w, acc1);
            }
            g_s[tid] = acc0 + acc1;
            __syncthreads();   // bar G: gates ready

            if (tid < LSTM_H) {
                float gi = g_s[tid];
                float gf = g_s[tid + 256];
                float gg = g_s[tid + 512];
                float go = g_s[tid + 768];
                c = sigmoidf_(gf) * c + sigmoidf_(gi) * tanhf_(gg);
                hlast = sigmoidf_(go) * tanhf_(c);
                // pack h into f16 pairs: even lane combines with odd partner
                uint32_t mine = (uint32_t)__half_as_ushort(__float2half(hlast));
                uint32_t partner = (uint32_t)__shfl_xor((int)mine, 1, 64);
                if ((tid & 1) == 0) h_u[tid >> 1] = (mine & 0xffffu) | (partner << 16);
            }
            __syncthreads();   // bar H: h_{t+1} visible for next dot
        }
    }

    if (tid < LSTM_H) {
        out[b * LSTM_H + tid]                   = hlast;  // h_T
        out[LSTM_B * LSTM_H + b * LSTM_H + tid] = c;      // c_T
    }
}

extern "C" void kernel_launch(void* const* d_in, const int* in_sizes, int n_in,
                              void* d_out, int out_size, void* d_ws, size_t ws_size,
                              hipStream_t stream) {
    const float* xs   = (const float*)d_in[0];  // [64,4096,256]
    const float* W_ih = (const float*)d_in[1];  // [1024,256]
    const float* W_hh = (const float*)d_in[2];  // [1024,256]
    const float* b    = (const float*)d_in[3];  // [1024]
    float* out = (float*)d_out;
    uint32_t* Wp = (uint32_t*)d_ws;             // 1 MiB packed f16 weights

    prep_weights<<<1024, 256, 0, stream>>>(W_ih, W_hh, Wp);
    lstm_r4<<<LSTM_B, 1024, 0, stream>>>(xs, b, (const uint4*)Wp, out);
}